// Round 10
// baseline (71.989 us; speedup 1.0000x reference)
//
#include <hip/hip_runtime.h>
#include <math.h>

#define TT 60
#define BB 64
#define STR 68
#define NBINS 45

// Native clang vector type: __builtin_nontemporal_load requires a pointer to
// scalar/vector-of-scalar, not HIP's struct float4 (r9 compile failure).
typedef float f32x4 __attribute__((ext_vector_type(4)));

// ---------------- Kernel 1: TKE (temporal variance) ----------------
// r1 structure exactly (best measured: 83us profiled), ONE change: loads are
// non-temporal (global_load_dwordx4 ... nt). r1-r8 established the read rate
// is pinned at ~2.9 TB/s regardless of occupancy (6->27 waves/CU), ILP (2->9
// loads in flight), layout (strided vs contiguous), and hit tier (L3-warm ==
// cold) -> suspected per-CU L1 miss-tracking / allocation cap. NT loads are
// the one untested load-path variable that changes L1 allocation behavior.
__global__ __launch_bounds__(256) void tke_kernel(const float* __restrict__ preds,
                                                  const float* __restrict__ trues,
                                                  float* __restrict__ tke) {
    int gtid  = blockIdx.x * 256 + threadIdx.x;
    int input = gtid >> 16;          // 65536 float4-threads per input
    int rem   = gtid & 65535;
    int b     = rem >> 10;           // batch
    int p4    = rem & 1023;          // float4 index within 64x64 image

    const f32x4* src  = (const f32x4*)(input ? trues : preds);
    const f32x4* base = src + (size_t)b * (TT * 2048) + p4;

    float su[4]  = {0, 0, 0, 0}, squ[4] = {0, 0, 0, 0};
    float sv[4]  = {0, 0, 0, 0}, sqv[4] = {0, 0, 0, 0};
    #pragma unroll 4
    for (int t = 0; t < TT; ++t) {
        f32x4 u = __builtin_nontemporal_load(base + t * 2048);          // c = 0
        f32x4 v = __builtin_nontemporal_load(base + t * 2048 + 1024);   // c = 1
        #pragma unroll
        for (int j = 0; j < 4; ++j) {
            float uu = u[j], vv = v[j];
            su[j]  += uu;  squ[j] += uu * uu;
            sv[j]  += vv;  sqv[j] += vv * vv;
        }
    }
    const float inv = 1.0f / 60.0f;
    float o[4];
    #pragma unroll
    for (int j = 0; j < 4; ++j) {
        float mu = su[j] * inv, mv = sv[j] * inv;
        o[j] = 0.5f * ((squ[j] * inv - mu * mu) + (sqv[j] * inv - mv * mv));
    }
    float4 outv; outv.x = o[0]; outv.y = o[1]; outv.z = o[2]; outv.w = o[3];
    ((float4*)tke)[(size_t)(input * BB + b) * 1024 + p4] = outv;
}

// ---------------- Kernel 2: 2D DFT + power + radial bin sums ----------------
// one block (512 threads) per image; 128 images (64 preds then 64 trues)
__global__ __launch_bounds__(512) void dft_kernel(const float* __restrict__ tke,
                                                  float* __restrict__ binsums) {
    __shared__ __align__(16) float tke_s[64 * 64];
    __shared__ __align__(16) float Gr[64 * STR];   // stored [x][k], stride 68
    __shared__ __align__(16) float Gi[64 * STR];
    __shared__ float ctab[64], stab[64];
    __shared__ float bins_s[NBINS];

    int tid = threadIdx.x;
    int img = blockIdx.x;

    if (tid < 64) {
        float ang = (float)tid * 0.09817477042468103871f;   // 2*pi/64
        float ss, cc;
        sincosf(ang, &ss, &cc);
        ctab[tid] = cc; stab[tid] = ss;
    }
    if (tid < NBINS) bins_s[tid] = 0.0f;

    // load TKE image to LDS
    {
        const float4* src = (const float4*)(tke + (size_t)img * 4096);
        float4* dst = (float4*)tke_s;
        for (int i = tid; i < 1024; i += 512) dst[i] = src[i];
    }
    __syncthreads();

    // Stage A: G[k][x] = sum_y tke[y][x] * exp(-2pi i k y / 64)
    // thread owns k = tid>>3 (0..63), x-range x0..x0+7
    {
        int k  = tid >> 3;
        int x0 = (tid & 7) * 8;
        float gr[8] = {0,0,0,0,0,0,0,0};
        float gi[8] = {0,0,0,0,0,0,0,0};
        for (int y = 0; y < 64; ++y) {
            float4 ta = *(const float4*)&tke_s[(y << 6) + x0];
            float4 tb = *(const float4*)&tke_s[(y << 6) + x0 + 4];
            float tv[8] = {ta.x, ta.y, ta.z, ta.w, tb.x, tb.y, tb.z, tb.w};
            int idx = (k * y) & 63;
            float cc = ctab[idx], ss = stab[idx];
            #pragma unroll
            for (int j = 0; j < 8; ++j) {
                gr[j] += cc * tv[j];
                gi[j] -= ss * tv[j];
            }
        }
        #pragma unroll
        for (int j = 0; j < 8; ++j) {           // transposed store: G[x][k]
            Gr[(x0 + j) * STR + k] = gr[j];
            Gi[(x0 + j) * STR + k] = gi[j];
        }
    }
    __syncthreads();

    // Stage B: F[k][l] = sum_x G[k][x] * exp(-2pi i l x / 64); power + binning
    // thread owns l = tid>>3 (0..63), k-range k0..k0+7
    {
        int l  = tid >> 3;
        int k0 = (tid & 7) * 8;
        float fr[8] = {0,0,0,0,0,0,0,0};
        float fi[8] = {0,0,0,0,0,0,0,0};
        for (int x = 0; x < 64; ++x) {
            float4 a0 = *(const float4*)&Gr[x * STR + k0];
            float4 a1 = *(const float4*)&Gr[x * STR + k0 + 4];
            float4 b0 = *(const float4*)&Gi[x * STR + k0];
            float4 b1 = *(const float4*)&Gi[x * STR + k0 + 4];
            float ar[8] = {a0.x, a0.y, a0.z, a0.w, a1.x, a1.y, a1.z, a1.w};
            float br[8] = {b0.x, b0.y, b0.z, b0.w, b1.x, b1.y, b1.z, b1.w};
            int idx = (l * x) & 63;
            float cc = ctab[idx], ss = stab[idx];
            #pragma unroll
            for (int j = 0; j < 8; ++j) {
                fr[j] += ar[j] * cc + br[j] * ss;
                fi[j] += br[j] * cc - ar[j] * ss;
            }
        }
        float fl = (float)((l + 32) & 63) - 31.5f;
        #pragma unroll
        for (int j = 0; j < 8; ++j) {
            int k = k0 + j;
            float fk = (float)((k + 32) & 63) - 31.5f;
            float r = sqrtf(fk * fk + fl * fl);
            int bin = (int)r;
            float pw = fr[j] * fr[j] + fi[j] * fi[j];
            atomicAdd(&bins_s[bin], pw);
        }
    }
    __syncthreads();
    if (tid < NBINS) binsums[img * NBINS + tid] = bins_s[tid];
}

// ---------------- Kernel 3: MSE over azimuthal spectra ----------------
__global__ __launch_bounds__(256) void loss_kernel(const float* __restrict__ binsums,
                                                   float* __restrict__ out) {
    __shared__ int   cnt[NBINS];
    __shared__ float part[256];
    int tid = threadIdx.x;
    if (tid < NBINS) cnt[tid] = 0;
    __syncthreads();
    for (int p = tid; p < 4096; p += 256) {
        float dy = (float)(p >> 6) - 31.5f;
        float dx = (float)(p & 63) - 31.5f;
        int bin = (int)sqrtf(dy * dy + dx * dx);
        atomicAdd(&cnt[bin], 1);
    }
    __syncthreads();
    float acc = 0.0f;
    for (int j = tid; j < BB * 43; j += 256) {
        int b   = j / 43;
        int bin = j - b * 43 + 1;           // returned bins are 1..43
        float n  = (float)cnt[bin];
        float st = binsums[(BB + b) * NBINS + bin] / n;   // trues
        float sp = binsums[b * NBINS + bin] / n;          // preds
        float d  = st - sp;
        acc += d * d;
    }
    part[tid] = acc;
    __syncthreads();
    for (int s = 128; s > 0; s >>= 1) {
        if (tid < s) part[tid] += part[tid + s];
        __syncthreads();
    }
    if (tid == 0) out[0] = part[0] * (1.0f / (BB * 43.0f));
}

extern "C" void kernel_launch(void* const* d_in, const int* in_sizes, int n_in,
                              void* d_out, int out_size, void* d_ws, size_t ws_size,
                              hipStream_t stream) {
    const float* preds = (const float*)d_in[0];
    const float* trues = (const float*)d_in[1];
    float* tke     = (float*)d_ws;                  // 2*64*4096 floats = 2 MB
    float* binsums = tke + 2 * BB * 4096;           // 128*45 floats

    tke_kernel<<<512, 256, 0, stream>>>(preds, trues, tke);
    dft_kernel<<<128, 512, 0, stream>>>(tke, binsums);
    loss_kernel<<<1, 256, 0, stream>>>(binsums, (float*)d_out);
}

// Round 11
// 70.425 us; speedup vs baseline: 1.0222x; 1.0222x over previous
//
#include <hip/hip_runtime.h>
#include <math.h>

#define TT 60
#define BB 64
#define STR 68
#define NBINS 45

typedef float f32x4 __attribute__((ext_vector_type(4)));

// ---------------- Kernel 1: TKE via global_load_lds DMA pipeline ----------------
// r1-r10 established: VGPR-path reads are pinned at ~2.9 TB/s regardless of
// occupancy/ILP/NT/layout (suspected per-CU L1 miss-tracking cap), while the
// write path hits 7.2 TB/s. The ONE untested read path is the global_load_lds
// DMA (no VGPR writeback, no L1 allocation) - the GEMM ladder's proven
// high-BW staging path. Wave-local: each wave stages and consumes only its
// own 1KB per buffer -> NO barriers. Ring of 4 t-slots, depth-3 prefetch,
// counted vmcnt(6) (T4: never drain to 0 in the loop).
__global__ __launch_bounds__(256) void tke_kernel(const float* __restrict__ preds,
                                                  const float* __restrict__ trues,
                                                  float* __restrict__ tke) {
    __shared__ __align__(16) float lds[4][2][1024];   // 4 t-slots x {u,v} x 4KB = 32KB

    int tid   = threadIdx.x;
    int bid   = blockIdx.x;
    int input = bid >> 8;            // 256 blocks per input
    int rem   = bid & 255;
    int b     = rem >> 2;            // batch
    int win   = rem & 3;             // 4KB pixel window within image
    int p4    = win * 256 + tid;     // float4 pixel index

    const float* src   = input ? trues : preds;
    // per-lane global float pointer; u(t) = gbase + t*8192, v(t) = u + 4096
    const float* gbase = src + (size_t)b * (TT * 8192) + (size_t)p4 * 4;

    int wave_off = (tid >> 6) << 8;  // wave-uniform LDS float offset (1KB/wave)

#define STAGE(SLOT, T) do {                                                           \
    const float* _gu = gbase + (size_t)(T) * 8192;                                    \
    __builtin_amdgcn_global_load_lds(_gu,        &lds[SLOT][0][wave_off], 16, 0, 0);  \
    __builtin_amdgcn_global_load_lds(_gu + 4096, &lds[SLOT][1][wave_off], 16, 0, 0);  \
} while (0)

#define WAITSB(N) do {                                                                \
    asm volatile("s_waitcnt vmcnt(" #N ")" ::: "memory");                             \
    __builtin_amdgcn_sched_barrier(0);                                                \
} while (0)

#define CONSUME(SLOT) do {                                                            \
    f32x4 u = *(const f32x4*)&lds[SLOT][0][tid * 4];                                  \
    f32x4 v = *(const f32x4*)&lds[SLOT][1][tid * 4];                                  \
    su += u; squ += u * u;                                                            \
    sv += v; sqv += v * v;                                                            \
} while (0)

    f32x4 su  = {0, 0, 0, 0}, squ = {0, 0, 0, 0};
    f32x4 sv  = {0, 0, 0, 0}, sqv = {0, 0, 0, 0};

    STAGE(0, 0);
    STAGE(1, 1);
    STAGE(2, 2);
    #pragma unroll 4
    for (int t = 0; t < 56; ++t) {       // stages 3..58, consumes 0..55
        STAGE((t + 3) & 3, t + 3);
        WAITSB(6);                        // stage t complete; 3 stages in flight
        CONSUME(t & 3);
    }
    STAGE(3, 59);                         // slot (56+3)&3 = 3
    WAITSB(6);  CONSUME(0);               // t=56, slot 0
    WAITSB(4);  CONSUME(1);               // t=57
    WAITSB(2);  CONSUME(2);               // t=58
    WAITSB(0);  CONSUME(3);               // t=59

#undef STAGE
#undef WAITSB
#undef CONSUME

    const float inv = 1.0f / 60.0f;
    f32x4 mu = su * inv, mv = sv * inv;
    f32x4 o  = 0.5f * ((squ * inv - mu * mu) + (sqv * inv - mv * mv));
    float4 outv; outv.x = o[0]; outv.y = o[1]; outv.z = o[2]; outv.w = o[3];
    ((float4*)tke)[(size_t)(input * BB + b) * 1024 + p4] = outv;
}

// ---------------- Kernel 2: 2D DFT + power + radial bin sums ----------------
// one block (512 threads) per image; 128 images (64 preds then 64 trues)
__global__ __launch_bounds__(512) void dft_kernel(const float* __restrict__ tke,
                                                  float* __restrict__ binsums) {
    __shared__ __align__(16) float tke_s[64 * 64];
    __shared__ __align__(16) float Gr[64 * STR];   // stored [x][k], stride 68
    __shared__ __align__(16) float Gi[64 * STR];
    __shared__ float ctab[64], stab[64];
    __shared__ float bins_s[NBINS];

    int tid = threadIdx.x;
    int img = blockIdx.x;

    if (tid < 64) {
        float ang = (float)tid * 0.09817477042468103871f;   // 2*pi/64
        float ss, cc;
        sincosf(ang, &ss, &cc);
        ctab[tid] = cc; stab[tid] = ss;
    }
    if (tid < NBINS) bins_s[tid] = 0.0f;

    // load TKE image to LDS
    {
        const float4* src = (const float4*)(tke + (size_t)img * 4096);
        float4* dst = (float4*)tke_s;
        for (int i = tid; i < 1024; i += 512) dst[i] = src[i];
    }
    __syncthreads();

    // Stage A: G[k][x] = sum_y tke[y][x] * exp(-2pi i k y / 64)
    // thread owns k = tid>>3 (0..63), x-range x0..x0+7
    {
        int k  = tid >> 3;
        int x0 = (tid & 7) * 8;
        float gr[8] = {0,0,0,0,0,0,0,0};
        float gi[8] = {0,0,0,0,0,0,0,0};
        for (int y = 0; y < 64; ++y) {
            float4 ta = *(const float4*)&tke_s[(y << 6) + x0];
            float4 tb = *(const float4*)&tke_s[(y << 6) + x0 + 4];
            float tv[8] = {ta.x, ta.y, ta.z, ta.w, tb.x, tb.y, tb.z, tb.w};
            int idx = (k * y) & 63;
            float cc = ctab[idx], ss = stab[idx];
            #pragma unroll
            for (int j = 0; j < 8; ++j) {
                gr[j] += cc * tv[j];
                gi[j] -= ss * tv[j];
            }
        }
        #pragma unroll
        for (int j = 0; j < 8; ++j) {           // transposed store: G[x][k]
            Gr[(x0 + j) * STR + k] = gr[j];
            Gi[(x0 + j) * STR + k] = gi[j];
        }
    }
    __syncthreads();

    // Stage B: F[k][l] = sum_x G[k][x] * exp(-2pi i l x / 64); power + binning
    // thread owns l = tid>>3 (0..63), k-range k0..k0+7
    {
        int l  = tid >> 3;
        int k0 = (tid & 7) * 8;
        float fr[8] = {0,0,0,0,0,0,0,0};
        float fi[8] = {0,0,0,0,0,0,0,0};
        for (int x = 0; x < 64; ++x) {
            float4 a0 = *(const float4*)&Gr[x * STR + k0];
            float4 a1 = *(const float4*)&Gr[x * STR + k0 + 4];
            float4 b0 = *(const float4*)&Gi[x * STR + k0];
            float4 b1 = *(const float4*)&Gi[x * STR + k0 + 4];
            float ar[8] = {a0.x, a0.y, a0.z, a0.w, a1.x, a1.y, a1.z, a1.w};
            float br[8] = {b0.x, b0.y, b0.z, b0.w, b1.x, b1.y, b1.z, b1.w};
            int idx = (l * x) & 63;
            float cc = ctab[idx], ss = stab[idx];
            #pragma unroll
            for (int j = 0; j < 8; ++j) {
                fr[j] += ar[j] * cc + br[j] * ss;
                fi[j] += br[j] * cc - ar[j] * ss;
            }
        }
        float fl = (float)((l + 32) & 63) - 31.5f;
        #pragma unroll
        for (int j = 0; j < 8; ++j) {
            int k = k0 + j;
            float fk = (float)((k + 32) & 63) - 31.5f;
            float r = sqrtf(fk * fk + fl * fl);
            int bin = (int)r;
            float pw = fr[j] * fr[j] + fi[j] * fi[j];
            atomicAdd(&bins_s[bin], pw);
        }
    }
    __syncthreads();
    if (tid < NBINS) binsums[img * NBINS + tid] = bins_s[tid];
}

// ---------------- Kernel 3: MSE over azimuthal spectra ----------------
__global__ __launch_bounds__(256) void loss_kernel(const float* __restrict__ binsums,
                                                   float* __restrict__ out) {
    __shared__ int   cnt[NBINS];
    __shared__ float part[256];
    int tid = threadIdx.x;
    if (tid < NBINS) cnt[tid] = 0;
    __syncthreads();
    for (int p = tid; p < 4096; p += 256) {
        float dy = (float)(p >> 6) - 31.5f;
        float dx = (float)(p & 63) - 31.5f;
        int bin = (int)sqrtf(dy * dy + dx * dx);
        atomicAdd(&cnt[bin], 1);
    }
    __syncthreads();
    float acc = 0.0f;
    for (int j = tid; j < BB * 43; j += 256) {
        int b   = j / 43;
        int bin = j - b * 43 + 1;           // returned bins are 1..43
        float n  = (float)cnt[bin];
        float st = binsums[(BB + b) * NBINS + bin] / n;   // trues
        float sp = binsums[b * NBINS + bin] / n;          // preds
        float d  = st - sp;
        acc += d * d;
    }
    part[tid] = acc;
    __syncthreads();
    for (int s = 128; s > 0; s >>= 1) {
        if (tid < s) part[tid] += part[tid + s];
        __syncthreads();
    }
    if (tid == 0) out[0] = part[0] * (1.0f / (BB * 43.0f));
}

extern "C" void kernel_launch(void* const* d_in, const int* in_sizes, int n_in,
                              void* d_out, int out_size, void* d_ws, size_t ws_size,
                              hipStream_t stream) {
    const float* preds = (const float*)d_in[0];
    const float* trues = (const float*)d_in[1];
    float* tke     = (float*)d_ws;                  // 2*64*4096 floats = 2 MB
    float* binsums = tke + 2 * BB * 4096;           // 128*45 floats

    tke_kernel<<<512, 256, 0, stream>>>(preds, trues, tke);
    dft_kernel<<<128, 512, 0, stream>>>(tke, binsums);
    loss_kernel<<<1, 256, 0, stream>>>(binsums, (float*)d_out);
}